// Round 4
// baseline (359.911 us; speedup 1.0000x reference)
//
#include <hip/hip_runtime.h>
#include <cstddef>
#include <cstdint>

// LinearAttention B=4,S=4096,D=1024,H=16,Hd=64.  M=16384.
// Round 4: kv_ksum gets transposed LDS staging (vector b128 fragment reads,
// was 320 scalar ds_read_u16/thread); chunks 16->8; cast_x+transpose_w fused.

typedef __attribute__((ext_vector_type(8))) __bf16 bf16x8;
typedef __attribute__((ext_vector_type(4))) __bf16 bf16x4;
typedef __attribute__((ext_vector_type(4))) float f32x4;

__device__ __forceinline__ void async_cp16(const void* g, void* s) {
    __builtin_amdgcn_global_load_lds(
        (__attribute__((address_space(1))) void*)g,
        (__attribute__((address_space(3))) void*)s, 16, 0, 0);
}

// ---------------------------------------------------------------------------
// 128x128 C-tile of A[.,1024]_bf16 x BT[1024,1024]_bf16^T, K=1024, BK=32.
// ---------------------------------------------------------------------------
__device__ __forceinline__ void mfma_core(const __bf16* __restrict__ A,
                                          const __bf16* __restrict__ BT,
                                          int mbase, int nbase,
                                          __bf16* As, __bf16* Bs,
                                          f32x4 acc[4][4])
{
    const int t    = threadIdx.x;
    const int lane = t & 63;
    const int wid  = t >> 6;
    const int wm   = (wid >> 1) * 64;
    const int wn   = (wid & 1) * 64;
    const int fr   = lane & 15;
    const int fq   = lane >> 4;
    const int srow = lane >> 2;
    const int skof = (lane & 3) * 8;

    const __bf16* arow0 = A  + (size_t)(mbase + wid * 32 + srow) * 1024 + skof;
    const __bf16* brow0 = BT + (size_t)(nbase + wid * 32 + srow) * 1024 + skof;

    for (int kt = 0; kt < 1024; kt += 32) {
        async_cp16(arow0 + kt,             As + (2 * wid + 0) * 512);
        async_cp16(arow0 + kt + 16 * 1024, As + (2 * wid + 1) * 512);
        async_cp16(brow0 + kt,             Bs + (2 * wid + 0) * 512);
        async_cp16(brow0 + kt + 16 * 1024, Bs + (2 * wid + 1) * 512);
        __syncthreads();

        bf16x8 af[4], bfr[4];
#pragma unroll
        for (int i = 0; i < 4; i++) {
            af[i]  = *(const bf16x8*)(As + (wm + i * 16 + fr) * 32 + fq * 8);
            bfr[i] = *(const bf16x8*)(Bs + (wn + i * 16 + fr) * 32 + fq * 8);
        }
#pragma unroll
        for (int i = 0; i < 4; i++)
#pragma unroll
            for (int j = 0; j < 4; j++)
                acc[i][j] = __builtin_amdgcn_mfma_f32_16x16x32_bf16(
                    af[i], bfr[j], acc[i][j], 0, 0, 0);
        __syncthreads();
    }
}

// ---------------------------------------------------------------------------
// QKV: grid=(128 mt, 24 nt); nt>>3: 0=q 1=k (both elu+1) 2=v. All bf16 out.
// ---------------------------------------------------------------------------
__global__ __launch_bounds__(256) void gemm_qkv_mfma(
    const __bf16* __restrict__ xb,
    const __bf16* __restrict__ wqt, const __bf16* __restrict__ wkt,
    const __bf16* __restrict__ wvt,
    const float* __restrict__ bq, const float* __restrict__ bk,
    const float* __restrict__ bv,
    __bf16* __restrict__ qfb, __bf16* __restrict__ kfb, __bf16* __restrict__ vb)
{
    __shared__ __bf16 As[128 * 32];
    __shared__ __bf16 Bs[128 * 32];
    f32x4 acc[4][4];
#pragma unroll
    for (int i = 0; i < 4; i++)
#pragma unroll
        for (int j = 0; j < 4; j++) acc[i][j] = (f32x4){0.f, 0.f, 0.f, 0.f};

    const int mt = blockIdx.x;
    const int nt = blockIdx.y;
    const int which = nt >> 3;
    const int nbase = (nt & 7) * 128;
    const int mbase = mt * 128;

    const __bf16* BT  = (which == 0) ? wqt : (which == 1) ? wkt : wvt;
    const float* bias = (which == 0) ? bq : (which == 1) ? bk : bv;
    __bf16* outp      = (which == 0) ? qfb : (which == 1) ? kfb : vb;
    const bool feat   = (which < 2);

    mfma_core(xb, BT, mbase, nbase, As, Bs, acc);

    const int t = threadIdx.x, lane = t & 63, wid = t >> 6;
    const int wm = (wid >> 1) * 64, wn = (wid & 1) * 64;
    const int fr = lane & 15, fq = lane >> 4;

#pragma unroll
    for (int i = 0; i < 4; i++)
#pragma unroll
        for (int j = 0; j < 4; j++) {
            const int col = nbase + wn + j * 16 + fr;
            const float bval = bias[col];
#pragma unroll
            for (int r = 0; r < 4; r++) {
                const int row = mbase + wm + i * 16 + fq * 4 + r;
                float vv = acc[i][j][r] + bval;
                if (feat) vv = (vv > 0.f) ? (vv + 1.f) : __expf(vv);
                outp[(size_t)row * 1024 + col] = (__bf16)vv;
            }
        }
}

// ---------------------------------------------------------------------------
// out = y @ WoT + bo (fp32). grid=(128 mt, 8 nt)
// ---------------------------------------------------------------------------
__global__ __launch_bounds__(256) void gemm_out_mfma(
    const __bf16* __restrict__ yb, const __bf16* __restrict__ wot,
    const float* __restrict__ bo, float* __restrict__ out)
{
    __shared__ __bf16 As[128 * 32];
    __shared__ __bf16 Bs[128 * 32];
    f32x4 acc[4][4];
#pragma unroll
    for (int i = 0; i < 4; i++)
#pragma unroll
        for (int j = 0; j < 4; j++) acc[i][j] = (f32x4){0.f, 0.f, 0.f, 0.f};

    const int mbase = blockIdx.x * 128;
    const int nbase = blockIdx.y * 128;

    mfma_core(yb, wot, mbase, nbase, As, Bs, acc);

    const int t = threadIdx.x, lane = t & 63, wid = t >> 6;
    const int wm = (wid >> 1) * 64, wn = (wid & 1) * 64;
    const int fr = lane & 15, fq = lane >> 4;

#pragma unroll
    for (int i = 0; i < 4; i++)
#pragma unroll
        for (int j = 0; j < 4; j++) {
            const int col = nbase + wn + j * 16 + fr;
            const float bval = bo[col];
#pragma unroll
            for (int r = 0; r < 4; r++) {
                const int row = mbase + wm + i * 16 + fq * 4 + r;
                out[(size_t)row * 1024 + col] = acc[i][j][r] + bval;
            }
        }
}

// ---------------------------------------------------------------------------
// kv partials: kvp[bh][chunk][m][d] = sum_{s in chunk} v[s][m]*kf[s][d]
// ksum partials via ones-A MFMA.  grid=(64 bh, 8 chunks of 512 s).
// Transposed staging: vT[m][s], kfT[d][s] (pitch 72) so ALL fragment
// reads are ds_read_b128 (k=s contiguous).  A=V^T, B=KF.
// ---------------------------------------------------------------------------
__global__ __launch_bounds__(256) void kv_ksum_mfma(
    const __bf16* __restrict__ kfb, const __bf16* __restrict__ vb,
    float* __restrict__ kvp, float* __restrict__ ksp)
{
    __shared__ __bf16 kfT[64 * 72];   // [d][s]
    __shared__ __bf16 vT[64 * 72];    // [m][s]

    const int bh = blockIdx.x;
    const int n = bh >> 4, h = bh & 15;
    const int chunk = blockIdx.y;
    const int t = threadIdx.x, lane = t & 63, w = t >> 6;
    const int fr = lane & 15, fq = lane >> 4;

    f32x4 acc[4];
#pragma unroll
    for (int j = 0; j < 4; j++) acc[j] = (f32x4){0.f, 0.f, 0.f, 0.f};
    f32x4 accks = (f32x4){0.f, 0.f, 0.f, 0.f};

    bf16x8 ones;
#pragma unroll
    for (int e = 0; e < 8; e++) ones[e] = (__bf16)1.0f;

    const size_t base = ((size_t)n * 4096 + (size_t)chunk * 512) * 1024 + h * 64;
    const int ss = t >> 2;           // staging row 0..63
    const int d0 = (t & 3) * 16;     // staging col base

    for (int tile = 0; tile < 8; tile++) {
        const size_t g = base + (size_t)(tile * 64 + ss) * 1024 + d0;
        bf16x8 ka = *(const bf16x8*)(kfb + g);
        bf16x8 kb = *(const bf16x8*)(kfb + g + 8);
        bf16x8 va = *(const bf16x8*)(vb + g);
        bf16x8 vc = *(const bf16x8*)(vb + g + 8);
#pragma unroll
        for (int e = 0; e < 8; e++) {
            kfT[(d0 + e) * 72 + ss]     = ka[e];
            kfT[(d0 + 8 + e) * 72 + ss] = kb[e];
            vT[(d0 + e) * 72 + ss]      = va[e];
            vT[(d0 + 8 + e) * 72 + ss]  = vc[e];
        }
        __syncthreads();

#pragma unroll
        for (int kk = 0; kk < 2; kk++) {
            bf16x8 af = *(const bf16x8*)(vT + (16 * w + fr) * 72 + kk * 32 + fq * 8);
            bf16x8 bfr[4];
#pragma unroll
            for (int j2 = 0; j2 < 4; j2++)
                bfr[j2] = *(const bf16x8*)(kfT + (16 * j2 + fr) * 72 + kk * 32 + fq * 8);
#pragma unroll
            for (int j2 = 0; j2 < 4; j2++)
                acc[j2] = __builtin_amdgcn_mfma_f32_16x16x32_bf16(
                    af, bfr[j2], acc[j2], 0, 0, 0);
            accks = __builtin_amdgcn_mfma_f32_16x16x32_bf16(
                ones, bfr[w], accks, 0, 0, 0);
        }
        __syncthreads();
    }

    const size_t pbase = ((size_t)bh * 8 + chunk) * 4096;
#pragma unroll
    for (int j2 = 0; j2 < 4; j2++)
#pragma unroll
        for (int r = 0; r < 4; r++) {
            int m = 16 * w + fq * 4 + r;
            int d = 16 * j2 + fr;
            kvp[pbase + m * 64 + d] = acc[j2][r];
        }
    if (fq == 0)
        ksp[((size_t)bh * 8 + chunk) * 64 + 16 * w + fr] = accks[0];
}

// ---------------------------------------------------------------------------
// reduce partials -> kvb bf16 [bh][m][d], ksumb bf16 [bh][d]
// ---------------------------------------------------------------------------
__global__ __launch_bounds__(256) void reduce_kv(
    const float* __restrict__ kvp, const float* __restrict__ ksp,
    __bf16* __restrict__ kvb, __bf16* __restrict__ ksumb)
{
    const int b = blockIdx.x;
    if (b < 1024) {
        int i = b * 256 + threadIdx.x;          // 0..262143
        int bh = i >> 12, md = i & 4095;
        float s = 0.f;
#pragma unroll
        for (int c = 0; c < 8; c++) s += kvp[((size_t)bh * 8 + c) * 4096 + md];
        kvb[i] = (__bf16)s;
    } else {
        int j = (b - 1024) * 256 + threadIdx.x; // 0..4095
        int bh = j >> 6, d = j & 63;
        float s = 0.f;
#pragma unroll
        for (int c = 0; c < 8; c++) s += ksp[((size_t)bh * 8 + c) * 64 + d];
        ksumb[j] = (__bf16)s;
    }
}

// ---------------------------------------------------------------------------
// y[g,h,m] = z * sum_d qf[g,h,d]*kv[bh,m,d], z = 1/(qf.ksum+eps)
// zden via MFMA with B[k][n] = ksum[k] (replicated).
// grid=(128 gtiles of 128, 16 h)
// ---------------------------------------------------------------------------
__global__ __launch_bounds__(256) void y_mfma(
    const __bf16* __restrict__ qfb, const __bf16* __restrict__ kvb,
    const __bf16* __restrict__ ksumb, __bf16* __restrict__ yb)
{
    __shared__ __bf16 qs[128 * 72];
    __shared__ __bf16 kvs[64 * 72];

    const int gbase = blockIdx.x * 128;
    const int h = blockIdx.y;
    const int bh = (gbase >> 12) * 16 + h;
    const int t = threadIdx.x, lane = t & 63, w = t >> 6;
    const int fr = lane & 15, fq = lane >> 4;

#pragma unroll
    for (int i = 0; i < 4; i++) {
        int idx = t + i * 256;                  // 0..1023
        int l = idx >> 3, d0 = (idx & 7) * 8;
        *(bf16x8*)(qs + l * 72 + d0) =
            *(const bf16x8*)(qfb + (size_t)(gbase + l) * 1024 + h * 64 + d0);
    }
#pragma unroll
    for (int i = 0; i < 2; i++) {
        int idx = t + i * 256;                  // 0..511
        int m = idx >> 3, d0 = (idx & 7) * 8;
        *(bf16x8*)(kvs + m * 72 + d0) =
            *(const bf16x8*)(kvb + (size_t)bh * 4096 + m * 64 + d0);
    }
    bf16x8 ksb[2];
#pragma unroll
    for (int kk = 0; kk < 2; kk++)
        ksb[kk] = *(const bf16x8*)(ksumb + bh * 64 + kk * 32 + fq * 8);
    __syncthreads();

    f32x4 acc[2][4], accz[2];
#pragma unroll
    for (int i = 0; i < 2; i++) {
        accz[i] = (f32x4){0.f, 0.f, 0.f, 0.f};
#pragma unroll
        for (int j = 0; j < 4; j++) acc[i][j] = (f32x4){0.f, 0.f, 0.f, 0.f};
    }

#pragma unroll
    for (int kk = 0; kk < 2; kk++) {
        bf16x8 af[2], bfr[4];
#pragma unroll
        for (int i = 0; i < 2; i++)
            af[i] = *(const bf16x8*)(qs + (32 * w + 16 * i + fr) * 72 + kk * 32 + fq * 8);
#pragma unroll
        for (int j = 0; j < 4; j++)
            bfr[j] = *(const bf16x8*)(kvs + (16 * j + fr) * 72 + kk * 32 + fq * 8);
#pragma unroll
        for (int i = 0; i < 2; i++) {
#pragma unroll
            for (int j = 0; j < 4; j++)
                acc[i][j] = __builtin_amdgcn_mfma_f32_16x16x32_bf16(
                    af[i], bfr[j], acc[i][j], 0, 0, 0);
            accz[i] = __builtin_amdgcn_mfma_f32_16x16x32_bf16(
                af[i], ksb[kk], accz[i], 0, 0, 0);
        }
    }

#pragma unroll
    for (int i = 0; i < 2; i++)
#pragma unroll
        for (int r = 0; r < 4; r++) {
            const float z = 1.0f / (accz[i][r] + 1e-6f);
            const int g = gbase + 32 * w + 16 * i + fq * 4 + r;
#pragma unroll
            for (int j = 0; j < 4; j++)
                yb[(size_t)g * 1024 + h * 64 + 16 * j + fr] =
                    (__bf16)(acc[i][j][r] * z);
        }
}

// ---------------------------------------------------------------------------
// prep: blocks [0,8192): cast x fp32->bf16 (8 els/thread)
//       blocks [8192,12288): transpose+cast the 4 weight matrices
// ---------------------------------------------------------------------------
__global__ __launch_bounds__(256) void prep(
    const float* __restrict__ x, __bf16* __restrict__ xb,
    const float* __restrict__ w0, const float* __restrict__ w1,
    const float* __restrict__ w2, const float* __restrict__ w3,
    __bf16* __restrict__ o0, __bf16* __restrict__ o1,
    __bf16* __restrict__ o2, __bf16* __restrict__ o3)
{
    if (blockIdx.x < 8192) {
        const size_t i = ((size_t)blockIdx.x * 256 + threadIdx.x) * 8;
        float4 a = *(const float4*)(x + i);
        float4 b = *(const float4*)(x + i + 4);
        bf16x8 o;
        o[0] = (__bf16)a.x; o[1] = (__bf16)a.y; o[2] = (__bf16)a.z; o[3] = (__bf16)a.w;
        o[4] = (__bf16)b.x; o[5] = (__bf16)b.y; o[6] = (__bf16)b.z; o[7] = (__bf16)b.w;
        *(bf16x8*)(xb + i) = o;
        return;
    }
    __shared__ float ld[32][33];
    const int bb = blockIdx.x - 8192;           // 0..4095
    const int wsel = bb >> 10;                  // 0..3
    const int kt = (bb & 1023) >> 5;            // 0..31
    const int nt = bb & 31;                     // 0..31
    const float* src = (wsel == 0) ? w0 : (wsel == 1) ? w1 : (wsel == 2) ? w2 : w3;
    __bf16* dst      = (wsel == 0) ? o0 : (wsel == 1) ? o1 : (wsel == 2) ? o2 : o3;

    const int kbase = kt * 32;
    const int nbase = nt * 32;
    const int t = threadIdx.x;
    const int r = t >> 3, c4 = (t & 7) * 4;

    float4 a = *(const float4*)(src + (size_t)(kbase + r) * 1024 + nbase + c4);
    ld[r][c4 + 0] = a.x; ld[r][c4 + 1] = a.y; ld[r][c4 + 2] = a.z; ld[r][c4 + 3] = a.w;
    __syncthreads();

    bf16x4 o;
    o[0] = (__bf16)ld[c4 + 0][r];
    o[1] = (__bf16)ld[c4 + 1][r];
    o[2] = (__bf16)ld[c4 + 2][r];
    o[3] = (__bf16)ld[c4 + 3][r];
    *(bf16x4*)(dst + (size_t)(nbase + r) * 1024 + kbase + c4) = o;
}

extern "C" void kernel_launch(void* const* d_in, const int* in_sizes, int n_in,
                              void* d_out, int out_size, void* d_ws, size_t ws_size,
                              hipStream_t stream)
{
    const float* x  = (const float*)d_in[0];
    const float* Wq = (const float*)d_in[1];
    const float* bq = (const float*)d_in[2];
    const float* Wk = (const float*)d_in[3];
    const float* bk = (const float*)d_in[4];
    const float* Wv = (const float*)d_in[5];
    const float* bv = (const float*)d_in[6];
    const float* Wo = (const float*)d_in[7];
    const float* bo = (const float*)d_in[8];
    float* out = (float*)d_out;

    __bf16* xb    = (__bf16*)d_ws;                   // 16777216
    __bf16* wqt   = xb + (size_t)16777216;           // 1048576 each
    __bf16* wkt   = wqt + 1048576;
    __bf16* wvt   = wkt + 1048576;
    __bf16* wot   = wvt + 1048576;
    __bf16* qfb   = wot + 1048576;                   // 16777216
    __bf16* kfb   = qfb + (size_t)16777216;          // 16777216 (reused as yb)
    __bf16* vb    = kfb + (size_t)16777216;          // 16777216
    float*  kvp   = (float*)(vb + (size_t)16777216); // 2097152 fp32 (8 MB)
    float*  ksp   = kvp + 2097152;                   // 32768 fp32
    __bf16* kvb   = (__bf16*)(ksp + 32768);          // 262144
    __bf16* ksumb = kvb + 262144;                    // 4096

    prep<<<dim3(12288), dim3(256), 0, stream>>>(
        x, xb, Wq, Wk, Wv, Wo, wqt, wkt, wvt, wot);

    gemm_qkv_mfma<<<dim3(128, 24), dim3(256), 0, stream>>>(
        xb, wqt, wkt, wvt, bq, bk, bv, qfb, kfb, vb);
    kv_ksum_mfma<<<dim3(64, 8), dim3(256), 0, stream>>>(kfb, vb, kvp, ksp);
    reduce_kv<<<dim3(1040), dim3(256), 0, stream>>>(kvp, ksp, kvb, ksumb);
    y_mfma<<<dim3(128, 16), dim3(256), 0, stream>>>(qfb, kvb, ksumb, kfb);
    gemm_out_mfma<<<dim3(128, 8), dim3(256), 0, stream>>>(kfb, wot, bo, out);
}